// Round 11
// baseline (243.698 us; speedup 1.0000x reference)
//
#include <hip/hip_runtime.h>
#include <math.h>

#define SEQ 4096
#define CH  256
#define NHT 8      // N * HEADS
#define DHD 64

// Q is pre-scaled by log2(e)/64 at projection time, so both attention passes
// compute exp2(S) with zero multiplies.
#define QSCALE 0.0225421092f

using bf16x8 = __attribute__((ext_vector_type(8))) short;
using f32x4  = __attribute__((ext_vector_type(4))) float;
typedef unsigned short u16;
typedef unsigned int   u32;

__device__ __forceinline__ u16 f2bf(float f) {
    u32 u = __float_as_uint(f);
    u = (u + 0x7fffu + ((u >> 16) & 1u)) >> 16;
    return (u16)u;
}
__device__ __forceinline__ float bf2f(u16 h) {
    return __uint_as_float(((u32)h) << 16);
}
// raw v_exp_f32 — exp2f without -ffast-math is an OCML call (~8 VALU ops)
__device__ __forceinline__ float fexp2(float x) {
    return __builtin_amdgcn_exp2f(x);
}

// ---------------------------------------------------------------------------
// Prep: weight pack (blocks 0..1279) + LN1 (blocks 1280..1535), one launch.
// ---------------------------------------------------------------------------
__global__ __launch_bounds__(256) void k_prep(const float* __restrict__ x,
                                              const float* __restrict__ ln1w,
                                              const float* __restrict__ ln1b,
                                              const float* __restrict__ WQ,
                                              const float* __restrict__ WK,
                                              const float* __restrict__ WV,
                                              const float* __restrict__ W1,
                                              const float* __restrict__ W2,
                                              u16* __restrict__ norm,
                                              u16* __restrict__ BtQKV,
                                              u16* __restrict__ W1t,
                                              u16* __restrict__ W2t)
{
    __shared__ float tile[32][257];
    __shared__ float mu[32], rs[32];
    int bid = blockIdx.x;
    int t = threadIdx.x;
    if (bid < 1280) {   // ---- pack ----
        int id = bid * 256 + t;
        if (id < 768 * 256) {
            int j = id >> 8, c = id & 255;
            int which = j >> 8, h = (j >> 6) & 3, d = j & 63;
            const float* W = (which == 0) ? WQ : (which == 1) ? WK : WV;
            BtQKV[id] = f2bf(W[(h * 256 + c) * 64 + d]);
        } else if (id < 768 * 256 + 65536) {
            int jj = id - 768 * 256;
            int j = jj >> 8, c = jj & 255;
            W1t[jj] = f2bf(W1[c * 256 + j]);
        } else if (id < 768 * 256 + 2 * 65536) {
            int jj = id - 768 * 256 - 65536;
            int j = jj >> 8, c = jj & 255;
            W2t[jj] = f2bf(W2[c * 256 + j]);
        }
        return;
    }
    // ---- LN1 ----
    int b2i = bid - 1280;
    int n = b2i >> 7, s0 = (b2i & 127) * 32;
    int sl = t & 31, cg = t >> 5;
    for (int cc = 0; cc < 256; cc += 8) {
        int c = cc + cg;
        tile[sl][c] = x[(n * 256 + c) * SEQ + s0 + sl];
    }
    __syncthreads();
    int wv = t >> 6, l = t & 63;
    for (int rr = 0; rr < 8; rr++) {
        int s = wv * 8 + rr;
        float a0 = tile[s][l], a1 = tile[s][l + 64], a2 = tile[s][l + 128], a3 = tile[s][l + 192];
        float sm = a0 + a1 + a2 + a3;
        float sq = a0 * a0 + a1 * a1 + a2 * a2 + a3 * a3;
        for (int off = 32; off; off >>= 1) { sm += __shfl_xor(sm, off); sq += __shfl_xor(sq, off); }
        if (l == 0) {
            float m = sm * (1.f / 256.f);
            mu[s] = m;
            rs[s] = rsqrtf(sq * (1.f / 256.f) - m * m + 1e-5f);
        }
    }
    __syncthreads();
    float ww = ln1w[t], bb = ln1b[t];
    for (int s = 0; s < 32; s++) {
        float v = (tile[s][t] - mu[s]) * rs[s] * ww + bb;
        norm[(n * SEQ + s0 + s) * 256 + t] = f2bf(v);
    }
}

// ---------------------------------------------------------------------------
// QKV projection, barrier-free (R4-proven). Q pre-scaled by QSCALE.
// V written directly transposed (Vt[nh][d][k], raw).
// ---------------------------------------------------------------------------
__global__ __launch_bounds__(256) void k_qkv(const u16* __restrict__ norm,
                                             const u16* __restrict__ Bt,
                                             u16* __restrict__ Qo,
                                             u16* __restrict__ Ko,
                                             u16* __restrict__ Vto)
{
    int m0 = blockIdx.x * 64, j0 = blockIdx.y * 128;
    int t = threadIdx.x, w = t >> 6, lane = t & 63, quad = lane >> 4, l16 = lane & 15;
    const u16* Ap = norm + (long)(m0 + w * 16 + l16) * 256;
    const u16* Bp = Bt + (long)j0 * 256;
    f32x4 z = {0.f, 0.f, 0.f, 0.f};
    f32x4 acc[8];
    #pragma unroll
    for (int j = 0; j < 8; j++) acc[j] = z;
    #pragma unroll
    for (int kc = 0; kc < 8; kc++) {
        bf16x8 a = *(const bf16x8*)&Ap[kc * 32 + quad * 8];
        #pragma unroll
        for (int j = 0; j < 8; j++) {
            bf16x8 b = *(const bf16x8*)&Bp[(long)(j * 16 + l16) * 256 + kc * 32 + quad * 8];
            acc[j] = __builtin_amdgcn_mfma_f32_16x16x32_bf16(a, b, acc[j], 0, 0, 0);
        }
    }
    #pragma unroll
    for (int j = 0; j < 8; j++) {
        int col = j0 + j * 16 + l16;
        int which = col >> 8, h = (col >> 6) & 3, d = col & 63;
        int m = m0 + w * 16 + quad * 4;
        int n = m >> 12, s = m & 4095;
        if (which == 2) {
            u16 h0 = f2bf(acc[j][0]), h1 = f2bf(acc[j][1]);
            u16 h2_ = f2bf(acc[j][2]), h3 = f2bf(acc[j][3]);
            uint2 pk;
            pk.x = (u32)h0 | ((u32)h1 << 16);
            pk.y = (u32)h2_ | ((u32)h3 << 16);
            *(uint2*)&Vto[((long)(n * 4 + h) * 64 + d) * SEQ + s] = pk;
        } else {
            u16* dst = (which == 0) ? Qo : Ko;
            float sc = (which == 0) ? QSCALE : 1.0f;
            #pragma unroll
            for (int r = 0; r < 4; r++)
                dst[((n * 4 + h) * SEQ + s + r) * 64 + d] = f2bf(acc[j][r] * sc);
        }
    }
}

// ---------------------------------------------------------------------------
// Pass 1, wave-split-q (R8-proven), raw v_exp_f32. Grid (32, 8, 4).
// ---------------------------------------------------------------------------
__global__ __launch_bounds__(256) void k_pass1(const u16* __restrict__ Q,
                                               const u16* __restrict__ Km,
                                               float* __restrict__ D4)
{
    __shared__ float Dred[128];
    int nh = blockIdx.y, k0 = blockIdx.x * 128, qc = blockIdx.z;
    const u16* Qh = Q + (long)nh * SEQ * 64;
    const u16* Kh = Km + (long)nh * SEQ * 64;
    int t = threadIdx.x, w = t >> 6, lane = t & 63, quad = lane >> 4, l16 = lane & 15;
    bf16x8 Kf[8][2];
    #pragma unroll
    for (int i = 0; i < 8; i++) {
        Kf[i][0] = *(const bf16x8*)&Kh[(k0 + i * 16 + l16) * 64 + quad * 8];
        Kf[i][1] = *(const bf16x8*)&Kh[(k0 + i * 16 + l16) * 64 + 32 + quad * 8];
    }
    if (t < 128) Dred[t] = 0.f;
    f32x4 z = {0.f, 0.f, 0.f, 0.f};
    float Dacc[8][4] = {};
    const int qw0 = qc * 1024 + w * 256;
    bf16x8 b0 = *(const bf16x8*)&Qh[(qw0 + l16) * 64 + quad * 8];
    bf16x8 b1 = *(const bf16x8*)&Qh[(qw0 + l16) * 64 + 32 + quad * 8];
    for (int step = 0; step < 16; step++) {
        int q = qw0 + step * 16;
        bf16x8 n0, n1;
        if (step < 15) {
            n0 = *(const bf16x8*)&Qh[(q + 16 + l16) * 64 + quad * 8];
            n1 = *(const bf16x8*)&Qh[(q + 16 + l16) * 64 + 32 + quad * 8];
        }
        #pragma unroll
        for (int i = 0; i < 8; i++) {
            f32x4 acc = z;
            acc = __builtin_amdgcn_mfma_f32_16x16x32_bf16(Kf[i][0], b0, acc, 0, 0, 0);
            acc = __builtin_amdgcn_mfma_f32_16x16x32_bf16(Kf[i][1], b1, acc, 0, 0, 0);
            #pragma unroll
            for (int r = 0; r < 4; r++) Dacc[i][r] += fexp2(acc[r]);
        }
        b0 = n0; b1 = n1;
    }
    #pragma unroll
    for (int i = 0; i < 8; i++)
        #pragma unroll
        for (int r = 0; r < 4; r++) {
            float v = Dacc[i][r];
            v += __shfl_xor(v, 1); v += __shfl_xor(v, 2);
            v += __shfl_xor(v, 4); v += __shfl_xor(v, 8);
            Dacc[i][r] = v;
        }
    __syncthreads();
    if (l16 == 0) {
        #pragma unroll
        for (int i = 0; i < 8; i++)
            #pragma unroll
            for (int r = 0; r < 4; r++)
                atomicAdd(&Dred[i * 16 + quad * 4 + r], Dacc[i][r]);
    }
    __syncthreads();
    if (t < 128) D4[((long)(qc * NHT + nh)) * SEQ + k0 + t] = Dred[t];
}

// ---------------------------------------------------------------------------
// Pass 2, wave-split-k, Q-TILE 128 (R11).  Qf[8][2] reused over the wave's
// whole 512-k range: K/V loads per MFMA halve (8:1) and the MFMA->exp chain
// gets 8 independent jq streams.  ~250 VGPR, __launch_bounds__(256,2) caps
// at 256 -> 2 waves/SIMD, grid 512 = exactly 2 blocks/CU (full residency).
// 1/D folded as exp2(S - Lk[k]) (R10-proven).  P written immediately (no pk
// buffer); kA/vb prefetched at half-body distance.  Zero main-loop barriers.
// Epilogue: sequential 4-wave reduction into red[128][68] (overlays lP).
// Grid (32 q-tiles, 8 nh, 2 k-chunks).
// ---------------------------------------------------------------------------
__global__ __launch_bounds__(256, 2) void k_pass2(const u16* __restrict__ Q,
                                                  const u16* __restrict__ Km,
                                                  const u16* __restrict__ Vt,
                                                  const float* __restrict__ D4,
                                                  float* __restrict__ acat2)
{
    __shared__ __align__(16) u16 lP[4][128][36];   // 36864 B
    __shared__ float Lk[2048];                     // 8192 B
    float (*red)[68] = (float(*)[68])lP;           // 34816 B overlay (epilogue)

    int nh = blockIdx.y, q0 = blockIdx.x * 128, kcid = blockIdx.z;
    int n = nh >> 2, h = nh & 3;
    const u16* Qh = Q + (long)nh * SEQ * 64;
    const u16* Kh = Km + (long)nh * SEQ * 64;
    const u16* Vh = Vt + (long)nh * 64 * SEQ;
    int t = threadIdx.x, w = t >> 6, lane = t & 63, quad = lane >> 4, l16 = lane & 15;
    const int kw0 = kcid * 2048 + w * 512;
    const int klw = w * 512;

    // ---- Lk[kl] = log2(sum of 4 D4 partials) over the block's 2048-k window
    {
        const float* Dp = D4 + (long)nh * SEQ + kcid * 2048;
        const long QS = (long)NHT * SEQ;
        #pragma unroll
        for (int off = 0; off < 8; off++) {
            int kl = off * 256 + t;
            float s = Dp[kl] + Dp[QS + kl] + Dp[2 * QS + kl] + Dp[3 * QS + kl];
            Lk[kl] = __log2f(s);
        }
    }
    // Q frags for the full 128-q tile + K(0) frags
    bf16x8 Qf[8][2];
    #pragma unroll
    for (int jq = 0; jq < 8; jq++)
        #pragma unroll
        for (int ch = 0; ch < 2; ch++)
            Qf[jq][ch] = *(const bf16x8*)&Qh[(q0 + jq * 16 + l16) * 64 + ch * 32 + quad * 8];
    bf16x8 kA[2][2];
    #pragma unroll
    for (int ksub = 0; ksub < 2; ksub++) {
        kA[ksub][0] = *(const bf16x8*)&Kh[(kw0 + ksub * 16 + l16) * 64 + quad * 8];
        kA[ksub][1] = *(const bf16x8*)&Kh[(kw0 + ksub * 16 + l16) * 64 + 32 + quad * 8];
    }
    bf16x8 vb[4];
    #pragma unroll
    for (int jd = 0; jd < 4; jd++)
        vb[jd] = *(const bf16x8*)&Vh[(jd * 16 + l16) * SEQ + kw0 + quad * 8];
    f32x4 z = {0.f, 0.f, 0.f, 0.f};
    f32x4 accO[8][4];
    #pragma unroll
    for (int jq = 0; jq < 8; jq++)
        #pragma unroll
        for (int jd = 0; jd < 4; jd++) accO[jq][jd] = z;
    __syncthreads();   // Lk ready

    for (int i = 0; i < 16; i++) {
        int k0 = kw0 + i * 32;
        // ST: 32 k x 128 q, immediate packed writes to own strip
        #pragma unroll
        for (int ksub = 0; ksub < 2; ksub++) {
            f32x4 Lv = *(const f32x4*)&Lk[klw + i * 32 + ksub * 16 + quad * 4];
            #pragma unroll
            for (int jq = 0; jq < 8; jq++) {
                f32x4 acc = z;
                acc = __builtin_amdgcn_mfma_f32_16x16x32_bf16(kA[ksub][0], Qf[jq][0], acc, 0, 0, 0);
                acc = __builtin_amdgcn_mfma_f32_16x16x32_bf16(kA[ksub][1], Qf[jq][1], acc, 0, 0, 0);
                u32 e0 = __float_as_uint(fexp2(acc[0] - Lv[0]));
                u32 e1 = __float_as_uint(fexp2(acc[1] - Lv[1]));
                u32 e2 = __float_as_uint(fexp2(acc[2] - Lv[2]));
                u32 e3 = __float_as_uint(fexp2(acc[3] - Lv[3]));
                uint2 pk;
                pk.x = __builtin_amdgcn_perm(e1, e0, 0x07060302u);
                pk.y = __builtin_amdgcn_perm(e3, e2, 0x07060302u);
                *(uint2*)&lP[w][jq * 16 + l16][ksub * 16 + quad * 4] = pk;
            }
        }
        // prefetch next K (half-body distance to use)
        if (i < 15) {
            #pragma unroll
            for (int ksub = 0; ksub < 2; ksub++) {
                kA[ksub][0] = *(const bf16x8*)&Kh[(k0 + 32 + ksub * 16 + l16) * 64 + quad * 8];
                kA[ksub][1] = *(const bf16x8*)&Kh[(k0 + 32 + ksub * 16 + l16) * 64 + 32 + quad * 8];
            }
        }
        // PV: own strip (in-order DS per wave -> no barrier)
        #pragma unroll
        for (int jq = 0; jq < 8; jq++) {
            bf16x8 pa = *(const bf16x8*)&lP[w][jq * 16 + l16][quad * 8];
            #pragma unroll
            for (int jd = 0; jd < 4; jd++)
                accO[jq][jd] = __builtin_amdgcn_mfma_f32_16x16x32_bf16(pa, vb[jd], accO[jq][jd], 0, 0, 0);
        }
        // prefetch next V
        if (i < 15) {
            #pragma unroll
            for (int jd = 0; jd < 4; jd++)
                vb[jd] = *(const bf16x8*)&Vh[(jd * 16 + l16) * SEQ + k0 + 32 + quad * 8];
        }
    }
    // ---- sequential 4-wave reduction into red (overlays lP) ----
    __syncthreads();
    for (int src = 0; src < 4; src++) {
        if (w == src) {
            #pragma unroll
            for (int jq = 0; jq < 8; jq++)
                #pragma unroll
                for (int jd = 0; jd < 4; jd++)
                    #pragma unroll
                    for (int r = 0; r < 4; r++) {
                        float* cell = &red[jq * 16 + quad * 4 + r][jd * 16 + l16];
                        if (src == 0) *cell = accO[jq][jd][r];
                        else          *cell += accO[jq][jd][r];
                    }
        }
        __syncthreads();
    }
    float* dst = acat2 + (long)kcid * 8192 * 256;
    #pragma unroll
    for (int p = 0; p < 8; p++) {
        int row = p * 16 + (t >> 4);
        int ch = (t & 15) * 4;
        float4 o = *(float4*)&red[row][ch];
        *(float4*)&dst[((long)n * SEQ + q0 + row) * 256 + h * 64 + ch] = o;
    }
}

// ---------------------------------------------------------------------------
// Fused tail: LN2 + MLP + residual + transposed store (R9-proven).
// ---------------------------------------------------------------------------
__global__ __launch_bounds__(256) void k_tail(const float* __restrict__ x,
                                              const float* __restrict__ acat2,
                                              const float* __restrict__ lnw,
                                              const float* __restrict__ lnb,
                                              const u16* __restrict__ W1t,
                                              const float* __restrict__ b1v,
                                              const u16* __restrict__ W2t,
                                              const float* __restrict__ b2v,
                                              float* __restrict__ out)
{
    __shared__ __align__(16) unsigned char smem[16448];  // tile fp32 / lT u16
    float (*tile)[257] = (float(*)[257])smem;            // [16][257]
    u16 (*lT)[264] = (u16(*)[264])smem;                  // [16][264] overlay
    __shared__ float mu[16], rs[16];
    __shared__ __align__(16) u16 lH[16][264];

    const long STRIDE = (long)8192 * 256;
    int m0 = blockIdx.x * 16;
    int n = m0 >> 12, s0 = m0 & 4095;
    int t = threadIdx.x, w = t >> 6, lane = t & 63, quad = lane >> 4, l16 = lane & 15;

    {
        int sl = t & 15, cg = t >> 4;
        for (int cc = 0; cc < 256; cc += 16) {
            int c = cc + cg;
            tile[sl][c] = x[(n * 256 + c) * SEQ + s0 + sl];
        }
    }
    __syncthreads();
    for (int s = 0; s < 16; s++) {
        long idx = (long)(m0 + s) * 256 + t;
        tile[s][t] += acat2[idx] + acat2[idx + STRIDE];
    }
    __syncthreads();
    {
        int l = t & 63;
        for (int rr = 0; rr < 4; rr++) {
            int s = w * 4 + rr;
            float a0 = tile[s][l], a1 = tile[s][l + 64], a2 = tile[s][l + 128], a3 = tile[s][l + 192];
            float sm = a0 + a1 + a2 + a3;
            float sq = a0 * a0 + a1 * a1 + a2 * a2 + a3 * a3;
            for (int off = 32; off; off >>= 1) { sm += __shfl_xor(sm, off); sq += __shfl_xor(sq, off); }
            if (l == 0) {
                float m = sm * (1.f / 256.f);
                mu[s] = m;
                rs[s] = rsqrtf(sq * (1.f / 256.f) - m * m + 1e-5f);
            }
        }
    }
    __syncthreads();
    {
        float ww = lnw[t], bb = lnb[t];
        for (int s = 0; s < 16; s++)
            lH[s][t] = f2bf((tile[s][t] - mu[s]) * rs[s] * ww + bb);
    }
    __syncthreads();

    f32x4 z = {0.f, 0.f, 0.f, 0.f};
    f32x4 acc1[4];
    #pragma unroll
    for (int js = 0; js < 4; js++) acc1[js] = z;
    #pragma unroll
    for (int kc = 0; kc < 8; kc++) {
        bf16x8 b = *(const bf16x8*)&lH[l16][kc * 32 + quad * 8];
        #pragma unroll
        for (int js = 0; js < 4; js++) {
            bf16x8 a = *(const bf16x8*)&W1t[(long)(w * 64 + js * 16 + l16) * 256 + kc * 32 + quad * 8];
            acc1[js] = __builtin_amdgcn_mfma_f32_16x16x32_bf16(a, b, acc1[js], 0, 0, 0);
        }
    }
    #pragma unroll
    for (int js = 0; js < 4; js++) {
        u32 e[4];
        #pragma unroll
        for (int r = 0; r < 4; r++) {
            int j = w * 64 + js * 16 + quad * 4 + r;
            float v = acc1[js][r] + b1v[j];
            float g = 0.5f * v * (1.f + erff(v * 0.70710678118f));
            u32 u = __float_as_uint(g);
            e[r] = u + 0x7fffu + ((u >> 16) & 1u);
        }
        uint2 pk;
        pk.x = __builtin_amdgcn_perm(e[1], e[0], 0x07060302u);
        pk.y = __builtin_amdgcn_perm(e[3], e[2], 0x07060302u);
        *(uint2*)&lT[l16][w * 64 + js * 16 + quad * 4] = pk;
    }
    __syncthreads();
    f32x4 acc2[4];
    #pragma unroll
    for (int cs = 0; cs < 4; cs++) acc2[cs] = z;
    #pragma unroll
    for (int kc = 0; kc < 8; kc++) {
        bf16x8 pa = *(const bf16x8*)&lT[l16][kc * 32 + quad * 8];
        #pragma unroll
        for (int cs = 0; cs < 4; cs++) {
            bf16x8 wb = *(const bf16x8*)&W2t[(long)(w * 64 + cs * 16 + l16) * 256 + kc * 32 + quad * 8];
            acc2[cs] = __builtin_amdgcn_mfma_f32_16x16x32_bf16(pa, wb, acc2[cs], 0, 0, 0);
        }
    }
    #pragma unroll
    for (int cs = 0; cs < 4; cs++) {
        int c = w * 64 + cs * 16 + l16;
        float bj = b2v[c];
        float vv[4];
        #pragma unroll
        for (int r = 0; r < 4; r++) {
            long idx = (long)(m0 + quad * 4 + r) * 256 + c;
            vv[r] = acc2[cs][r] + bj + acat2[idx] + acat2[idx + STRIDE];
        }
        float4 o = make_float4(vv[0], vv[1], vv[2], vv[3]);
        *(float4*)&out[((long)n * 256 + c) * SEQ + s0 + quad * 4] = o;
    }
}

// ---------------------------------------------------------------------------
extern "C" void kernel_launch(void* const* d_in, const int* in_sizes, int n_in,
                              void* d_out, int out_size, void* d_ws, size_t ws_size,
                              hipStream_t stream) {
    const float* x    = (const float*)d_in[0];
    const float* ln1w = (const float*)d_in[1];
    const float* ln1b = (const float*)d_in[2];
    const float* WQ   = (const float*)d_in[3];
    const float* WK   = (const float*)d_in[4];
    const float* WV   = (const float*)d_in[5];
    const float* ln2w = (const float*)d_in[6];
    const float* ln2b = (const float*)d_in[7];
    const float* W1   = (const float*)d_in[8];
    const float* b1   = (const float*)d_in[9];
    const float* W2   = (const float*)d_in[10];
    const float* b2   = (const float*)d_in[11];
    float* out = (float*)d_out;

    char* p = (char*)d_ws;
    u16* norm   = (u16*)p;   p += (size_t)8192 * 256 * 2;
    u16* BtQKV  = (u16*)p;   p += (size_t)768 * 256 * 2;
    u16* W1t    = (u16*)p;   p += (size_t)256 * 256 * 2;
    u16* W2t    = (u16*)p;   p += (size_t)256 * 256 * 2;
    u16* Qb     = (u16*)p;   p += (size_t)NHT * SEQ * 64 * 2;
    u16* Kb     = (u16*)p;   p += (size_t)NHT * SEQ * 64 * 2;
    u16* VtT    = (u16*)p;   p += (size_t)NHT * SEQ * 64 * 2;
    float* D4   = (float*)p; p += (size_t)4 * NHT * SEQ * 4;
    float* acat2= (float*)p; p += (size_t)2 * 8192 * 256 * 4;

    k_prep<<<1536, 256, 0, stream>>>(x, ln1w, ln1b, WQ, WK, WV, W1, W2,
                                     norm, BtQKV, W1t, W2t);
    k_qkv<<<dim3(128, 6), 256, 0, stream>>>(norm, BtQKV, Qb, Kb, VtT);
    k_pass1<<<dim3(32, 8, 4), 256, 0, stream>>>(Qb, Kb, D4);
    k_pass2<<<dim3(32, 8, 2), 256, 0, stream>>>(Qb, Kb, VtT, D4, acat2);
    k_tail<<<512, 256, 0, stream>>>(x, acat2, ln2w, ln2b, W1t, b1, W2t, b2, out);
}

// Round 12
// 240.014 us; speedup vs baseline: 1.0153x; 1.0153x over previous
//
#include <hip/hip_runtime.h>
#include <math.h>

#define SEQ 4096
#define CH  256
#define NHT 8      // N * HEADS
#define DHD 64

// Q is pre-scaled by log2(e)/64 at projection time, so both attention passes
// compute exp2(S) with zero multiplies.
#define QSCALE 0.0225421092f

using bf16x8 = __attribute__((ext_vector_type(8))) short;
using f32x4  = __attribute__((ext_vector_type(4))) float;
typedef unsigned short u16;
typedef unsigned int   u32;

__device__ __forceinline__ u16 f2bf(float f) {
    u32 u = __float_as_uint(f);
    u = (u + 0x7fffu + ((u >> 16) & 1u)) >> 16;
    return (u16)u;
}
__device__ __forceinline__ float bf2f(u16 h) {
    return __uint_as_float(((u32)h) << 16);
}
// raw v_exp_f32 — exp2f without -ffast-math is an OCML call (~8 VALU ops)
__device__ __forceinline__ float fexp2(float x) {
    return __builtin_amdgcn_exp2f(x);
}

// ---------------------------------------------------------------------------
// Prep: weight pack (blocks 0..1279) + LN1 (blocks 1280..1535), one launch.
// ---------------------------------------------------------------------------
__global__ __launch_bounds__(256) void k_prep(const float* __restrict__ x,
                                              const float* __restrict__ ln1w,
                                              const float* __restrict__ ln1b,
                                              const float* __restrict__ WQ,
                                              const float* __restrict__ WK,
                                              const float* __restrict__ WV,
                                              const float* __restrict__ W1,
                                              const float* __restrict__ W2,
                                              u16* __restrict__ norm,
                                              u16* __restrict__ BtQKV,
                                              u16* __restrict__ W1t,
                                              u16* __restrict__ W2t)
{
    __shared__ float tile[32][257];
    __shared__ float mu[32], rs[32];
    int bid = blockIdx.x;
    int t = threadIdx.x;
    if (bid < 1280) {   // ---- pack ----
        int id = bid * 256 + t;
        if (id < 768 * 256) {
            int j = id >> 8, c = id & 255;
            int which = j >> 8, h = (j >> 6) & 3, d = j & 63;
            const float* W = (which == 0) ? WQ : (which == 1) ? WK : WV;
            BtQKV[id] = f2bf(W[(h * 256 + c) * 64 + d]);
        } else if (id < 768 * 256 + 65536) {
            int jj = id - 768 * 256;
            int j = jj >> 8, c = jj & 255;
            W1t[jj] = f2bf(W1[c * 256 + j]);
        } else if (id < 768 * 256 + 2 * 65536) {
            int jj = id - 768 * 256 - 65536;
            int j = jj >> 8, c = jj & 255;
            W2t[jj] = f2bf(W2[c * 256 + j]);
        }
        return;
    }
    // ---- LN1 ----
    int b2i = bid - 1280;
    int n = b2i >> 7, s0 = (b2i & 127) * 32;
    int sl = t & 31, cg = t >> 5;
    for (int cc = 0; cc < 256; cc += 8) {
        int c = cc + cg;
        tile[sl][c] = x[(n * 256 + c) * SEQ + s0 + sl];
    }
    __syncthreads();
    int wv = t >> 6, l = t & 63;
    for (int rr = 0; rr < 8; rr++) {
        int s = wv * 8 + rr;
        float a0 = tile[s][l], a1 = tile[s][l + 64], a2 = tile[s][l + 128], a3 = tile[s][l + 192];
        float sm = a0 + a1 + a2 + a3;
        float sq = a0 * a0 + a1 * a1 + a2 * a2 + a3 * a3;
        for (int off = 32; off; off >>= 1) { sm += __shfl_xor(sm, off); sq += __shfl_xor(sq, off); }
        if (l == 0) {
            float m = sm * (1.f / 256.f);
            mu[s] = m;
            rs[s] = rsqrtf(sq * (1.f / 256.f) - m * m + 1e-5f);
        }
    }
    __syncthreads();
    float ww = ln1w[t], bb = ln1b[t];
    for (int s = 0; s < 32; s++) {
        float v = (tile[s][t] - mu[s]) * rs[s] * ww + bb;
        norm[(n * SEQ + s0 + s) * 256 + t] = f2bf(v);
    }
}

// ---------------------------------------------------------------------------
// QKV projection, barrier-free (R4-proven). Q pre-scaled by QSCALE.
// V written directly transposed (Vt[nh][d][k], raw).
// ---------------------------------------------------------------------------
__global__ __launch_bounds__(256) void k_qkv(const u16* __restrict__ norm,
                                             const u16* __restrict__ Bt,
                                             u16* __restrict__ Qo,
                                             u16* __restrict__ Ko,
                                             u16* __restrict__ Vto)
{
    int m0 = blockIdx.x * 64, j0 = blockIdx.y * 128;
    int t = threadIdx.x, w = t >> 6, lane = t & 63, quad = lane >> 4, l16 = lane & 15;
    const u16* Ap = norm + (long)(m0 + w * 16 + l16) * 256;
    const u16* Bp = Bt + (long)j0 * 256;
    f32x4 z = {0.f, 0.f, 0.f, 0.f};
    f32x4 acc[8];
    #pragma unroll
    for (int j = 0; j < 8; j++) acc[j] = z;
    #pragma unroll
    for (int kc = 0; kc < 8; kc++) {
        bf16x8 a = *(const bf16x8*)&Ap[kc * 32 + quad * 8];
        #pragma unroll
        for (int j = 0; j < 8; j++) {
            bf16x8 b = *(const bf16x8*)&Bp[(long)(j * 16 + l16) * 256 + kc * 32 + quad * 8];
            acc[j] = __builtin_amdgcn_mfma_f32_16x16x32_bf16(a, b, acc[j], 0, 0, 0);
        }
    }
    #pragma unroll
    for (int j = 0; j < 8; j++) {
        int col = j0 + j * 16 + l16;
        int which = col >> 8, h = (col >> 6) & 3, d = col & 63;
        int m = m0 + w * 16 + quad * 4;
        int n = m >> 12, s = m & 4095;
        if (which == 2) {
            u16 h0 = f2bf(acc[j][0]), h1 = f2bf(acc[j][1]);
            u16 h2_ = f2bf(acc[j][2]), h3 = f2bf(acc[j][3]);
            uint2 pk;
            pk.x = (u32)h0 | ((u32)h1 << 16);
            pk.y = (u32)h2_ | ((u32)h3 << 16);
            *(uint2*)&Vto[((long)(n * 4 + h) * 64 + d) * SEQ + s] = pk;
        } else {
            u16* dst = (which == 0) ? Qo : Ko;
            float sc = (which == 0) ? QSCALE : 1.0f;
            #pragma unroll
            for (int r = 0; r < 4; r++)
                dst[((n * 4 + h) * SEQ + s + r) * 64 + d] = f2bf(acc[j][r] * sc);
        }
    }
}

// ---------------------------------------------------------------------------
// Pass 1, wave-split-q, raw v_exp_f32.  R12: 2 q-chunks (grid (32,8,2), 512
// blocks = 2/CU), each wave owns a private 1024-q range, 32 steps.
// ---------------------------------------------------------------------------
__global__ __launch_bounds__(256) void k_pass1(const u16* __restrict__ Q,
                                               const u16* __restrict__ Km,
                                               float* __restrict__ D2)
{
    __shared__ float Dred[128];
    int nh = blockIdx.y, k0 = blockIdx.x * 128, qc = blockIdx.z;
    const u16* Qh = Q + (long)nh * SEQ * 64;
    const u16* Kh = Km + (long)nh * SEQ * 64;
    int t = threadIdx.x, w = t >> 6, lane = t & 63, quad = lane >> 4, l16 = lane & 15;
    bf16x8 Kf[8][2];
    #pragma unroll
    for (int i = 0; i < 8; i++) {
        Kf[i][0] = *(const bf16x8*)&Kh[(k0 + i * 16 + l16) * 64 + quad * 8];
        Kf[i][1] = *(const bf16x8*)&Kh[(k0 + i * 16 + l16) * 64 + 32 + quad * 8];
    }
    if (t < 128) Dred[t] = 0.f;
    f32x4 z = {0.f, 0.f, 0.f, 0.f};
    float Dacc[8][4] = {};
    const int qw0 = qc * 2048 + w * 512;
    bf16x8 b0 = *(const bf16x8*)&Qh[(qw0 + l16) * 64 + quad * 8];
    bf16x8 b1 = *(const bf16x8*)&Qh[(qw0 + l16) * 64 + 32 + quad * 8];
    for (int step = 0; step < 32; step++) {
        int q = qw0 + step * 16;
        bf16x8 n0, n1;
        if (step < 31) {
            n0 = *(const bf16x8*)&Qh[(q + 16 + l16) * 64 + quad * 8];
            n1 = *(const bf16x8*)&Qh[(q + 16 + l16) * 64 + 32 + quad * 8];
        }
        #pragma unroll
        for (int i = 0; i < 8; i++) {
            f32x4 acc = z;
            acc = __builtin_amdgcn_mfma_f32_16x16x32_bf16(Kf[i][0], b0, acc, 0, 0, 0);
            acc = __builtin_amdgcn_mfma_f32_16x16x32_bf16(Kf[i][1], b1, acc, 0, 0, 0);
            #pragma unroll
            for (int r = 0; r < 4; r++) Dacc[i][r] += fexp2(acc[r]);
        }
        b0 = n0; b1 = n1;
    }
    #pragma unroll
    for (int i = 0; i < 8; i++)
        #pragma unroll
        for (int r = 0; r < 4; r++) {
            float v = Dacc[i][r];
            v += __shfl_xor(v, 1); v += __shfl_xor(v, 2);
            v += __shfl_xor(v, 4); v += __shfl_xor(v, 8);
            Dacc[i][r] = v;
        }
    __syncthreads();
    if (l16 == 0) {
        #pragma unroll
        for (int i = 0; i < 8; i++)
            #pragma unroll
            for (int r = 0; r < 4; r++)
                atomicAdd(&Dred[i * 16 + quad * 4 + r], Dacc[i][r]);
    }
    __syncthreads();
    if (t < 128) D2[((long)(qc * NHT + nh)) * SEQ + k0 + t] = Dred[t];
}

// ---------------------------------------------------------------------------
// Pass 2, wave-split-k, q-tile 128 (R11-proven).  R12: Lk folds 2 partials.
// Grid (32 q-tiles, 8 nh, 2 k-chunks).
// ---------------------------------------------------------------------------
__global__ __launch_bounds__(256, 2) void k_pass2(const u16* __restrict__ Q,
                                                  const u16* __restrict__ Km,
                                                  const u16* __restrict__ Vt,
                                                  const float* __restrict__ D2,
                                                  float* __restrict__ acat2)
{
    __shared__ __align__(16) u16 lP[4][128][36];   // 36864 B
    __shared__ float Lk[2048];                     // 8192 B
    float (*red)[68] = (float(*)[68])lP;           // 34816 B overlay (epilogue)

    int nh = blockIdx.y, q0 = blockIdx.x * 128, kcid = blockIdx.z;
    int n = nh >> 2, h = nh & 3;
    const u16* Qh = Q + (long)nh * SEQ * 64;
    const u16* Kh = Km + (long)nh * SEQ * 64;
    const u16* Vh = Vt + (long)nh * 64 * SEQ;
    int t = threadIdx.x, w = t >> 6, lane = t & 63, quad = lane >> 4, l16 = lane & 15;
    const int kw0 = kcid * 2048 + w * 512;
    const int klw = w * 512;

    // ---- Lk[kl] = log2(sum of 2 D partials) over the block's 2048-k window
    {
        const float* Dp = D2 + (long)nh * SEQ + kcid * 2048;
        const long QS = (long)NHT * SEQ;
        #pragma unroll
        for (int off = 0; off < 8; off++) {
            int kl = off * 256 + t;
            Lk[kl] = __log2f(Dp[kl] + Dp[QS + kl]);
        }
    }
    // Q frags for the full 128-q tile + K(0) frags
    bf16x8 Qf[8][2];
    #pragma unroll
    for (int jq = 0; jq < 8; jq++)
        #pragma unroll
        for (int ch = 0; ch < 2; ch++)
            Qf[jq][ch] = *(const bf16x8*)&Qh[(q0 + jq * 16 + l16) * 64 + ch * 32 + quad * 8];
    bf16x8 kA[2][2];
    #pragma unroll
    for (int ksub = 0; ksub < 2; ksub++) {
        kA[ksub][0] = *(const bf16x8*)&Kh[(kw0 + ksub * 16 + l16) * 64 + quad * 8];
        kA[ksub][1] = *(const bf16x8*)&Kh[(kw0 + ksub * 16 + l16) * 64 + 32 + quad * 8];
    }
    bf16x8 vb[4];
    #pragma unroll
    for (int jd = 0; jd < 4; jd++)
        vb[jd] = *(const bf16x8*)&Vh[(jd * 16 + l16) * SEQ + kw0 + quad * 8];
    f32x4 z = {0.f, 0.f, 0.f, 0.f};
    f32x4 accO[8][4];
    #pragma unroll
    for (int jq = 0; jq < 8; jq++)
        #pragma unroll
        for (int jd = 0; jd < 4; jd++) accO[jq][jd] = z;
    __syncthreads();   // Lk ready

    for (int i = 0; i < 16; i++) {
        int k0 = kw0 + i * 32;
        #pragma unroll
        for (int ksub = 0; ksub < 2; ksub++) {
            f32x4 Lv = *(const f32x4*)&Lk[klw + i * 32 + ksub * 16 + quad * 4];
            #pragma unroll
            for (int jq = 0; jq < 8; jq++) {
                f32x4 acc = z;
                acc = __builtin_amdgcn_mfma_f32_16x16x32_bf16(kA[ksub][0], Qf[jq][0], acc, 0, 0, 0);
                acc = __builtin_amdgcn_mfma_f32_16x16x32_bf16(kA[ksub][1], Qf[jq][1], acc, 0, 0, 0);
                u32 e0 = __float_as_uint(fexp2(acc[0] - Lv[0]));
                u32 e1 = __float_as_uint(fexp2(acc[1] - Lv[1]));
                u32 e2 = __float_as_uint(fexp2(acc[2] - Lv[2]));
                u32 e3 = __float_as_uint(fexp2(acc[3] - Lv[3]));
                uint2 pk;
                pk.x = __builtin_amdgcn_perm(e1, e0, 0x07060302u);
                pk.y = __builtin_amdgcn_perm(e3, e2, 0x07060302u);
                *(uint2*)&lP[w][jq * 16 + l16][ksub * 16 + quad * 4] = pk;
            }
        }
        if (i < 15) {
            #pragma unroll
            for (int ksub = 0; ksub < 2; ksub++) {
                kA[ksub][0] = *(const bf16x8*)&Kh[(k0 + 32 + ksub * 16 + l16) * 64 + quad * 8];
                kA[ksub][1] = *(const bf16x8*)&Kh[(k0 + 32 + ksub * 16 + l16) * 64 + 32 + quad * 8];
            }
        }
        #pragma unroll
        for (int jq = 0; jq < 8; jq++) {
            bf16x8 pa = *(const bf16x8*)&lP[w][jq * 16 + l16][quad * 8];
            #pragma unroll
            for (int jd = 0; jd < 4; jd++)
                accO[jq][jd] = __builtin_amdgcn_mfma_f32_16x16x32_bf16(pa, vb[jd], accO[jq][jd], 0, 0, 0);
        }
        if (i < 15) {
            #pragma unroll
            for (int jd = 0; jd < 4; jd++)
                vb[jd] = *(const bf16x8*)&Vh[(jd * 16 + l16) * SEQ + k0 + 32 + quad * 8];
        }
    }
    // ---- sequential 4-wave reduction into red (overlays lP) ----
    __syncthreads();
    for (int src = 0; src < 4; src++) {
        if (w == src) {
            #pragma unroll
            for (int jq = 0; jq < 8; jq++)
                #pragma unroll
                for (int jd = 0; jd < 4; jd++)
                    #pragma unroll
                    for (int r = 0; r < 4; r++) {
                        float* cell = &red[jq * 16 + quad * 4 + r][jd * 16 + l16];
                        if (src == 0) *cell = accO[jq][jd][r];
                        else          *cell += accO[jq][jd][r];
                    }
        }
        __syncthreads();
    }
    float* dst = acat2 + (long)kcid * 8192 * 256;
    #pragma unroll
    for (int p = 0; p < 8; p++) {
        int row = p * 16 + (t >> 4);
        int ch = (t & 15) * 4;
        float4 o = *(float4*)&red[row][ch];
        *(float4*)&dst[((long)n * SEQ + q0 + row) * 256 + h * 64 + ch] = o;
    }
}

// ---------------------------------------------------------------------------
// Fused tail: LN2 + MLP + residual + transposed store.  R12: the folded
// attention residual is cached in LDS (aF) during phase A, so the epilogue
// reads LDS instead of re-reading 64 MB of acat2 from HBM.
// ---------------------------------------------------------------------------
__global__ __launch_bounds__(256) void k_tail(const float* __restrict__ x,
                                              const float* __restrict__ acat2,
                                              const float* __restrict__ lnw,
                                              const float* __restrict__ lnb,
                                              const u16* __restrict__ W1t,
                                              const float* __restrict__ b1v,
                                              const u16* __restrict__ W2t,
                                              const float* __restrict__ b2v,
                                              float* __restrict__ out)
{
    __shared__ __align__(16) unsigned char smem[16448];  // tile fp32 / lT u16
    float (*tile)[257] = (float(*)[257])smem;            // [16][257]
    u16 (*lT)[264] = (u16(*)[264])smem;                  // [16][264] overlay
    __shared__ float aF[16][257];                        // folded acat cache
    __shared__ float mu[16], rs[16];
    __shared__ __align__(16) u16 lH[16][264];

    const long STRIDE = (long)8192 * 256;
    int m0 = blockIdx.x * 16;
    int n = m0 >> 12, s0 = m0 & 4095;
    int t = threadIdx.x, w = t >> 6, lane = t & 63, quad = lane >> 4, l16 = lane & 15;

    {
        int sl = t & 15, cg = t >> 4;
        for (int cc = 0; cc < 256; cc += 16) {
            int c = cc + cg;
            tile[sl][c] = x[(n * 256 + c) * SEQ + s0 + sl];
        }
    }
    __syncthreads();
    for (int s = 0; s < 16; s++) {
        long idx = (long)(m0 + s) * 256 + t;
        float a = acat2[idx] + acat2[idx + STRIDE];
        aF[s][t] = a;
        tile[s][t] += a;
    }
    __syncthreads();
    {
        int l = t & 63;
        for (int rr = 0; rr < 4; rr++) {
            int s = w * 4 + rr;
            float a0 = tile[s][l], a1 = tile[s][l + 64], a2 = tile[s][l + 128], a3 = tile[s][l + 192];
            float sm = a0 + a1 + a2 + a3;
            float sq = a0 * a0 + a1 * a1 + a2 * a2 + a3 * a3;
            for (int off = 32; off; off >>= 1) { sm += __shfl_xor(sm, off); sq += __shfl_xor(sq, off); }
            if (l == 0) {
                float m = sm * (1.f / 256.f);
                mu[s] = m;
                rs[s] = rsqrtf(sq * (1.f / 256.f) - m * m + 1e-5f);
            }
        }
    }
    __syncthreads();
    {
        float ww = lnw[t], bb = lnb[t];
        for (int s = 0; s < 16; s++)
            lH[s][t] = f2bf((tile[s][t] - mu[s]) * rs[s] * ww + bb);
    }
    __syncthreads();

    f32x4 z = {0.f, 0.f, 0.f, 0.f};
    f32x4 acc1[4];
    #pragma unroll
    for (int js = 0; js < 4; js++) acc1[js] = z;
    #pragma unroll
    for (int kc = 0; kc < 8; kc++) {
        bf16x8 b = *(const bf16x8*)&lH[l16][kc * 32 + quad * 8];
        #pragma unroll
        for (int js = 0; js < 4; js++) {
            bf16x8 a = *(const bf16x8*)&W1t[(long)(w * 64 + js * 16 + l16) * 256 + kc * 32 + quad * 8];
            acc1[js] = __builtin_amdgcn_mfma_f32_16x16x32_bf16(a, b, acc1[js], 0, 0, 0);
        }
    }
    #pragma unroll
    for (int js = 0; js < 4; js++) {
        u32 e[4];
        #pragma unroll
        for (int r = 0; r < 4; r++) {
            int j = w * 64 + js * 16 + quad * 4 + r;
            float v = acc1[js][r] + b1v[j];
            float g = 0.5f * v * (1.f + erff(v * 0.70710678118f));
            u32 u = __float_as_uint(g);
            e[r] = u + 0x7fffu + ((u >> 16) & 1u);
        }
        uint2 pk;
        pk.x = __builtin_amdgcn_perm(e[1], e[0], 0x07060302u);
        pk.y = __builtin_amdgcn_perm(e[3], e[2], 0x07060302u);
        *(uint2*)&lT[l16][w * 64 + js * 16 + quad * 4] = pk;
    }
    __syncthreads();
    f32x4 acc2[4];
    #pragma unroll
    for (int cs = 0; cs < 4; cs++) acc2[cs] = z;
    #pragma unroll
    for (int kc = 0; kc < 8; kc++) {
        bf16x8 pa = *(const bf16x8*)&lT[l16][kc * 32 + quad * 8];
        #pragma unroll
        for (int cs = 0; cs < 4; cs++) {
            bf16x8 wb = *(const bf16x8*)&W2t[(long)(w * 64 + cs * 16 + l16) * 256 + kc * 32 + quad * 8];
            acc2[cs] = __builtin_amdgcn_mfma_f32_16x16x32_bf16(pa, wb, acc2[cs], 0, 0, 0);
        }
    }
    #pragma unroll
    for (int cs = 0; cs < 4; cs++) {
        int c = w * 64 + cs * 16 + l16;
        float bj = b2v[c];
        float vv[4];
        #pragma unroll
        for (int r = 0; r < 4; r++)
            vv[r] = acc2[cs][r] + bj + aF[quad * 4 + r][c];
        float4 o = make_float4(vv[0], vv[1], vv[2], vv[3]);
        *(float4*)&out[((long)n * 256 + c) * SEQ + s0 + quad * 4] = o;
    }
}

// ---------------------------------------------------------------------------
extern "C" void kernel_launch(void* const* d_in, const int* in_sizes, int n_in,
                              void* d_out, int out_size, void* d_ws, size_t ws_size,
                              hipStream_t stream) {
    const float* x    = (const float*)d_in[0];
    const float* ln1w = (const float*)d_in[1];
    const float* ln1b = (const float*)d_in[2];
    const float* WQ   = (const float*)d_in[3];
    const float* WK   = (const float*)d_in[4];
    const float* WV   = (const float*)d_in[5];
    const float* ln2w = (const float*)d_in[6];
    const float* ln2b = (const float*)d_in[7];
    const float* W1   = (const float*)d_in[8];
    const float* b1   = (const float*)d_in[9];
    const float* W2   = (const float*)d_in[10];
    const float* b2   = (const float*)d_in[11];
    float* out = (float*)d_out;

    char* p = (char*)d_ws;
    u16* norm   = (u16*)p;   p += (size_t)8192 * 256 * 2;
    u16* BtQKV  = (u16*)p;   p += (size_t)768 * 256 * 2;
    u16* W1t    = (u16*)p;   p += (size_t)256 * 256 * 2;
    u16* W2t    = (u16*)p;   p += (size_t)256 * 256 * 2;
    u16* Qb     = (u16*)p;   p += (size_t)NHT * SEQ * 64 * 2;
    u16* Kb     = (u16*)p;   p += (size_t)NHT * SEQ * 64 * 2;
    u16* VtT    = (u16*)p;   p += (size_t)NHT * SEQ * 64 * 2;
    float* D2   = (float*)p; p += (size_t)2 * NHT * SEQ * 4;
    float* acat2= (float*)p; p += (size_t)2 * 8192 * 256 * 4;

    k_prep<<<1536, 256, 0, stream>>>(x, ln1w, ln1b, WQ, WK, WV, W1, W2,
                                     norm, BtQKV, W1t, W2t);
    k_qkv<<<dim3(128, 6), 256, 0, stream>>>(norm, BtQKV, Qb, Kb, VtT);
    k_pass1<<<dim3(32, 8, 2), 256, 0, stream>>>(Qb, Kb, D2);
    k_pass2<<<dim3(32, 8, 2), 256, 0, stream>>>(Qb, Kb, VtT, D2, acat2);
    k_tail<<<512, 256, 0, stream>>>(x, acat2, ln2w, ln2b, W1t, b1, W2t, b2, out);
}

// Round 13
// 231.794 us; speedup vs baseline: 1.0514x; 1.0355x over previous
//
#include <hip/hip_runtime.h>
#include <math.h>

#define SEQ 4096
#define CH  256
#define NHT 8      // N * HEADS
#define DHD 64

// Q is pre-scaled by log2(e)/64 at projection time, so both attention passes
// compute exp2(S) with zero multiplies.
#define QSCALE 0.0225421092f

using bf16x8 = __attribute__((ext_vector_type(8))) short;
using f32x4  = __attribute__((ext_vector_type(4))) float;
typedef unsigned short u16;
typedef unsigned int   u32;

__device__ __forceinline__ u16 f2bf(float f) {
    u32 u = __float_as_uint(f);
    u = (u + 0x7fffu + ((u >> 16) & 1u)) >> 16;
    return (u16)u;
}
__device__ __forceinline__ float bf2f(u16 h) {
    return __uint_as_float(((u32)h) << 16);
}
// raw v_exp_f32 — exp2f without -ffast-math is an OCML call (~8 VALU ops)
__device__ __forceinline__ float fexp2(float x) {
    return __builtin_amdgcn_exp2f(x);
}

// ---------------------------------------------------------------------------
// Prep: weight pack (blocks 0..1279) + LN1 (blocks 1280..1535), one launch.
// ---------------------------------------------------------------------------
__global__ __launch_bounds__(256) void k_prep(const float* __restrict__ x,
                                              const float* __restrict__ ln1w,
                                              const float* __restrict__ ln1b,
                                              const float* __restrict__ WQ,
                                              const float* __restrict__ WK,
                                              const float* __restrict__ WV,
                                              const float* __restrict__ W1,
                                              const float* __restrict__ W2,
                                              u16* __restrict__ norm,
                                              u16* __restrict__ BtQKV,
                                              u16* __restrict__ W1t,
                                              u16* __restrict__ W2t)
{
    __shared__ float tile[32][257];
    __shared__ float mu[32], rs[32];
    int bid = blockIdx.x;
    int t = threadIdx.x;
    if (bid < 1280) {   // ---- pack ----
        int id = bid * 256 + t;
        if (id < 768 * 256) {
            int j = id >> 8, c = id & 255;
            int which = j >> 8, h = (j >> 6) & 3, d = j & 63;
            const float* W = (which == 0) ? WQ : (which == 1) ? WK : WV;
            BtQKV[id] = f2bf(W[(h * 256 + c) * 64 + d]);
        } else if (id < 768 * 256 + 65536) {
            int jj = id - 768 * 256;
            int j = jj >> 8, c = jj & 255;
            W1t[jj] = f2bf(W1[c * 256 + j]);
        } else if (id < 768 * 256 + 2 * 65536) {
            int jj = id - 768 * 256 - 65536;
            int j = jj >> 8, c = jj & 255;
            W2t[jj] = f2bf(W2[c * 256 + j]);
        }
        return;
    }
    // ---- LN1 ----
    int b2i = bid - 1280;
    int n = b2i >> 7, s0 = (b2i & 127) * 32;
    int sl = t & 31, cg = t >> 5;
    for (int cc = 0; cc < 256; cc += 8) {
        int c = cc + cg;
        tile[sl][c] = x[(n * 256 + c) * SEQ + s0 + sl];
    }
    __syncthreads();
    int wv = t >> 6, l = t & 63;
    for (int rr = 0; rr < 8; rr++) {
        int s = wv * 8 + rr;
        float a0 = tile[s][l], a1 = tile[s][l + 64], a2 = tile[s][l + 128], a3 = tile[s][l + 192];
        float sm = a0 + a1 + a2 + a3;
        float sq = a0 * a0 + a1 * a1 + a2 * a2 + a3 * a3;
        for (int off = 32; off; off >>= 1) { sm += __shfl_xor(sm, off); sq += __shfl_xor(sq, off); }
        if (l == 0) {
            float m = sm * (1.f / 256.f);
            mu[s] = m;
            rs[s] = rsqrtf(sq * (1.f / 256.f) - m * m + 1e-5f);
        }
    }
    __syncthreads();
    float ww = ln1w[t], bb = ln1b[t];
    for (int s = 0; s < 32; s++) {
        float v = (tile[s][t] - mu[s]) * rs[s] * ww + bb;
        norm[(n * SEQ + s0 + s) * 256 + t] = f2bf(v);
    }
}

// ---------------------------------------------------------------------------
// QKV projection, barrier-free (R4-proven). Q pre-scaled by QSCALE.
// V written directly transposed (Vt[nh][d][k], raw).
// ---------------------------------------------------------------------------
__global__ __launch_bounds__(256) void k_qkv(const u16* __restrict__ norm,
                                             const u16* __restrict__ Bt,
                                             u16* __restrict__ Qo,
                                             u16* __restrict__ Ko,
                                             u16* __restrict__ Vto)
{
    int m0 = blockIdx.x * 64, j0 = blockIdx.y * 128;
    int t = threadIdx.x, w = t >> 6, lane = t & 63, quad = lane >> 4, l16 = lane & 15;
    const u16* Ap = norm + (long)(m0 + w * 16 + l16) * 256;
    const u16* Bp = Bt + (long)j0 * 256;
    f32x4 z = {0.f, 0.f, 0.f, 0.f};
    f32x4 acc[8];
    #pragma unroll
    for (int j = 0; j < 8; j++) acc[j] = z;
    #pragma unroll
    for (int kc = 0; kc < 8; kc++) {
        bf16x8 a = *(const bf16x8*)&Ap[kc * 32 + quad * 8];
        #pragma unroll
        for (int j = 0; j < 8; j++) {
            bf16x8 b = *(const bf16x8*)&Bp[(long)(j * 16 + l16) * 256 + kc * 32 + quad * 8];
            acc[j] = __builtin_amdgcn_mfma_f32_16x16x32_bf16(a, b, acc[j], 0, 0, 0);
        }
    }
    #pragma unroll
    for (int j = 0; j < 8; j++) {
        int col = j0 + j * 16 + l16;
        int which = col >> 8, h = (col >> 6) & 3, d = col & 63;
        int m = m0 + w * 16 + quad * 4;
        int n = m >> 12, s = m & 4095;
        if (which == 2) {
            u16 h0 = f2bf(acc[j][0]), h1 = f2bf(acc[j][1]);
            u16 h2_ = f2bf(acc[j][2]), h3 = f2bf(acc[j][3]);
            uint2 pk;
            pk.x = (u32)h0 | ((u32)h1 << 16);
            pk.y = (u32)h2_ | ((u32)h3 << 16);
            *(uint2*)&Vto[((long)(n * 4 + h) * 64 + d) * SEQ + s] = pk;
        } else {
            u16* dst = (which == 0) ? Qo : Ko;
            float sc = (which == 0) ? QSCALE : 1.0f;
            #pragma unroll
            for (int r = 0; r < 4; r++)
                dst[((n * 4 + h) * SEQ + s + r) * 64 + d] = f2bf(acc[j][r] * sc);
        }
    }
}

// ---------------------------------------------------------------------------
// Pass 1, wave-split-q, raw v_exp_f32.  2 q-chunks (grid (32,8,2), 512
// blocks = 2/CU), each wave owns a private 1024-q range, 32 steps.
// ---------------------------------------------------------------------------
__global__ __launch_bounds__(256) void k_pass1(const u16* __restrict__ Q,
                                               const u16* __restrict__ Km,
                                               float* __restrict__ D2)
{
    __shared__ float Dred[128];
    int nh = blockIdx.y, k0 = blockIdx.x * 128, qc = blockIdx.z;
    const u16* Qh = Q + (long)nh * SEQ * 64;
    const u16* Kh = Km + (long)nh * SEQ * 64;
    int t = threadIdx.x, w = t >> 6, lane = t & 63, quad = lane >> 4, l16 = lane & 15;
    bf16x8 Kf[8][2];
    #pragma unroll
    for (int i = 0; i < 8; i++) {
        Kf[i][0] = *(const bf16x8*)&Kh[(k0 + i * 16 + l16) * 64 + quad * 8];
        Kf[i][1] = *(const bf16x8*)&Kh[(k0 + i * 16 + l16) * 64 + 32 + quad * 8];
    }
    if (t < 128) Dred[t] = 0.f;
    f32x4 z = {0.f, 0.f, 0.f, 0.f};
    float Dacc[8][4] = {};
    const int qw0 = qc * 2048 + w * 512;
    bf16x8 b0 = *(const bf16x8*)&Qh[(qw0 + l16) * 64 + quad * 8];
    bf16x8 b1 = *(const bf16x8*)&Qh[(qw0 + l16) * 64 + 32 + quad * 8];
    for (int step = 0; step < 32; step++) {
        int q = qw0 + step * 16;
        bf16x8 n0, n1;
        if (step < 31) {
            n0 = *(const bf16x8*)&Qh[(q + 16 + l16) * 64 + quad * 8];
            n1 = *(const bf16x8*)&Qh[(q + 16 + l16) * 64 + 32 + quad * 8];
        }
        #pragma unroll
        for (int i = 0; i < 8; i++) {
            f32x4 acc = z;
            acc = __builtin_amdgcn_mfma_f32_16x16x32_bf16(Kf[i][0], b0, acc, 0, 0, 0);
            acc = __builtin_amdgcn_mfma_f32_16x16x32_bf16(Kf[i][1], b1, acc, 0, 0, 0);
            #pragma unroll
            for (int r = 0; r < 4; r++) Dacc[i][r] += fexp2(acc[r]);
        }
        b0 = n0; b1 = n1;
    }
    #pragma unroll
    for (int i = 0; i < 8; i++)
        #pragma unroll
        for (int r = 0; r < 4; r++) {
            float v = Dacc[i][r];
            v += __shfl_xor(v, 1); v += __shfl_xor(v, 2);
            v += __shfl_xor(v, 4); v += __shfl_xor(v, 8);
            Dacc[i][r] = v;
        }
    __syncthreads();
    if (l16 == 0) {
        #pragma unroll
        for (int i = 0; i < 8; i++)
            #pragma unroll
            for (int r = 0; r < 4; r++)
                atomicAdd(&Dred[i * 16 + quad * 4 + r], Dacc[i][r]);
    }
    __syncthreads();
    if (t < 128) D2[((long)(qc * NHT + nh)) * SEQ + k0 + t] = Dred[t];
}

// ---------------------------------------------------------------------------
// Pass 2, wave-split-k, q-tile 128.  R13: __launch_bounds__(256,1) — the
// (256,2) bound made the allocator target 4 waves/SIMD (128 VGPR) and spill
// ~66 MB/dispatch to scratch, for occupancy the 2-block/CU grid can't use.
// (256,1) lets it keep Qf(64)+accO(128)+prefetch(32) in ~240 regs, no spill.
// Grid (32 q-tiles, 8 nh, 2 k-chunks).
// ---------------------------------------------------------------------------
__global__ __launch_bounds__(256, 1) void k_pass2(const u16* __restrict__ Q,
                                                  const u16* __restrict__ Km,
                                                  const u16* __restrict__ Vt,
                                                  const float* __restrict__ D2,
                                                  float* __restrict__ acat2)
{
    __shared__ __align__(16) u16 lP[4][128][36];   // 36864 B
    __shared__ float Lk[2048];                     // 8192 B
    float (*red)[68] = (float(*)[68])lP;           // 34816 B overlay (epilogue)

    int nh = blockIdx.y, q0 = blockIdx.x * 128, kcid = blockIdx.z;
    int n = nh >> 2, h = nh & 3;
    const u16* Qh = Q + (long)nh * SEQ * 64;
    const u16* Kh = Km + (long)nh * SEQ * 64;
    const u16* Vh = Vt + (long)nh * 64 * SEQ;
    int t = threadIdx.x, w = t >> 6, lane = t & 63, quad = lane >> 4, l16 = lane & 15;
    const int kw0 = kcid * 2048 + w * 512;
    const int klw = w * 512;

    // ---- Lk[kl] = log2(sum of 2 D partials) over the block's 2048-k window
    {
        const float* Dp = D2 + (long)nh * SEQ + kcid * 2048;
        const long QS = (long)NHT * SEQ;
        #pragma unroll
        for (int off = 0; off < 8; off++) {
            int kl = off * 256 + t;
            Lk[kl] = __log2f(Dp[kl] + Dp[QS + kl]);
        }
    }
    // Q frags for the full 128-q tile + K(0) frags
    bf16x8 Qf[8][2];
    #pragma unroll
    for (int jq = 0; jq < 8; jq++)
        #pragma unroll
        for (int ch = 0; ch < 2; ch++)
            Qf[jq][ch] = *(const bf16x8*)&Qh[(q0 + jq * 16 + l16) * 64 + ch * 32 + quad * 8];
    bf16x8 kA[2][2];
    #pragma unroll
    for (int ksub = 0; ksub < 2; ksub++) {
        kA[ksub][0] = *(const bf16x8*)&Kh[(kw0 + ksub * 16 + l16) * 64 + quad * 8];
        kA[ksub][1] = *(const bf16x8*)&Kh[(kw0 + ksub * 16 + l16) * 64 + 32 + quad * 8];
    }
    bf16x8 vb[4];
    #pragma unroll
    for (int jd = 0; jd < 4; jd++)
        vb[jd] = *(const bf16x8*)&Vh[(jd * 16 + l16) * SEQ + kw0 + quad * 8];
    f32x4 z = {0.f, 0.f, 0.f, 0.f};
    f32x4 accO[8][4];
    #pragma unroll
    for (int jq = 0; jq < 8; jq++)
        #pragma unroll
        for (int jd = 0; jd < 4; jd++) accO[jq][jd] = z;
    __syncthreads();   // Lk ready

    for (int i = 0; i < 16; i++) {
        int k0 = kw0 + i * 32;
        #pragma unroll
        for (int ksub = 0; ksub < 2; ksub++) {
            f32x4 Lv = *(const f32x4*)&Lk[klw + i * 32 + ksub * 16 + quad * 4];
            #pragma unroll
            for (int jq = 0; jq < 8; jq++) {
                f32x4 acc = z;
                acc = __builtin_amdgcn_mfma_f32_16x16x32_bf16(kA[ksub][0], Qf[jq][0], acc, 0, 0, 0);
                acc = __builtin_amdgcn_mfma_f32_16x16x32_bf16(kA[ksub][1], Qf[jq][1], acc, 0, 0, 0);
                u32 e0 = __float_as_uint(fexp2(acc[0] - Lv[0]));
                u32 e1 = __float_as_uint(fexp2(acc[1] - Lv[1]));
                u32 e2 = __float_as_uint(fexp2(acc[2] - Lv[2]));
                u32 e3 = __float_as_uint(fexp2(acc[3] - Lv[3]));
                uint2 pk;
                pk.x = __builtin_amdgcn_perm(e1, e0, 0x07060302u);
                pk.y = __builtin_amdgcn_perm(e3, e2, 0x07060302u);
                *(uint2*)&lP[w][jq * 16 + l16][ksub * 16 + quad * 4] = pk;
            }
        }
        if (i < 15) {
            #pragma unroll
            for (int ksub = 0; ksub < 2; ksub++) {
                kA[ksub][0] = *(const bf16x8*)&Kh[(k0 + 32 + ksub * 16 + l16) * 64 + quad * 8];
                kA[ksub][1] = *(const bf16x8*)&Kh[(k0 + 32 + ksub * 16 + l16) * 64 + 32 + quad * 8];
            }
        }
        #pragma unroll
        for (int jq = 0; jq < 8; jq++) {
            bf16x8 pa = *(const bf16x8*)&lP[w][jq * 16 + l16][quad * 8];
            #pragma unroll
            for (int jd = 0; jd < 4; jd++)
                accO[jq][jd] = __builtin_amdgcn_mfma_f32_16x16x32_bf16(pa, vb[jd], accO[jq][jd], 0, 0, 0);
        }
        if (i < 15) {
            #pragma unroll
            for (int jd = 0; jd < 4; jd++)
                vb[jd] = *(const bf16x8*)&Vh[(jd * 16 + l16) * SEQ + k0 + 32 + quad * 8];
        }
    }
    // ---- sequential 4-wave reduction into red (overlays lP) ----
    __syncthreads();
    for (int src = 0; src < 4; src++) {
        if (w == src) {
            #pragma unroll
            for (int jq = 0; jq < 8; jq++)
                #pragma unroll
                for (int jd = 0; jd < 4; jd++)
                    #pragma unroll
                    for (int r = 0; r < 4; r++) {
                        float* cell = &red[jq * 16 + quad * 4 + r][jd * 16 + l16];
                        if (src == 0) *cell = accO[jq][jd][r];
                        else          *cell += accO[jq][jd][r];
                    }
        }
        __syncthreads();
    }
    float* dst = acat2 + (long)kcid * 8192 * 256;
    #pragma unroll
    for (int p = 0; p < 8; p++) {
        int row = p * 16 + (t >> 4);
        int ch = (t & 15) * 4;
        float4 o = *(float4*)&red[row][ch];
        *(float4*)&dst[((long)n * SEQ + q0 + row) * 256 + h * 64 + ch] = o;
    }
}

// ---------------------------------------------------------------------------
// Fused tail: LN2 + MLP + residual + transposed store (R12-proven: folded
// attention residual cached in LDS, no epilogue HBM re-read).
// ---------------------------------------------------------------------------
__global__ __launch_bounds__(256) void k_tail(const float* __restrict__ x,
                                              const float* __restrict__ acat2,
                                              const float* __restrict__ lnw,
                                              const float* __restrict__ lnb,
                                              const u16* __restrict__ W1t,
                                              const float* __restrict__ b1v,
                                              const u16* __restrict__ W2t,
                                              const float* __restrict__ b2v,
                                              float* __restrict__ out)
{
    __shared__ __align__(16) unsigned char smem[16448];  // tile fp32 / lT u16
    float (*tile)[257] = (float(*)[257])smem;            // [16][257]
    u16 (*lT)[264] = (u16(*)[264])smem;                  // [16][264] overlay
    __shared__ float aF[16][257];                        // folded acat cache
    __shared__ float mu[16], rs[16];
    __shared__ __align__(16) u16 lH[16][264];

    const long STRIDE = (long)8192 * 256;
    int m0 = blockIdx.x * 16;
    int n = m0 >> 12, s0 = m0 & 4095;
    int t = threadIdx.x, w = t >> 6, lane = t & 63, quad = lane >> 4, l16 = lane & 15;

    {
        int sl = t & 15, cg = t >> 4;
        for (int cc = 0; cc < 256; cc += 16) {
            int c = cc + cg;
            tile[sl][c] = x[(n * 256 + c) * SEQ + s0 + sl];
        }
    }
    __syncthreads();
    for (int s = 0; s < 16; s++) {
        long idx = (long)(m0 + s) * 256 + t;
        float a = acat2[idx] + acat2[idx + STRIDE];
        aF[s][t] = a;
        tile[s][t] += a;
    }
    __syncthreads();
    {
        int l = t & 63;
        for (int rr = 0; rr < 4; rr++) {
            int s = w * 4 + rr;
            float a0 = tile[s][l], a1 = tile[s][l + 64], a2 = tile[s][l + 128], a3 = tile[s][l + 192];
            float sm = a0 + a1 + a2 + a3;
            float sq = a0 * a0 + a1 * a1 + a2 * a2 + a3 * a3;
            for (int off = 32; off; off >>= 1) { sm += __shfl_xor(sm, off); sq += __shfl_xor(sq, off); }
            if (l == 0) {
                float m = sm * (1.f / 256.f);
                mu[s] = m;
                rs[s] = rsqrtf(sq * (1.f / 256.f) - m * m + 1e-5f);
            }
        }
    }
    __syncthreads();
    {
        float ww = lnw[t], bb = lnb[t];
        for (int s = 0; s < 16; s++)
            lH[s][t] = f2bf((tile[s][t] - mu[s]) * rs[s] * ww + bb);
    }
    __syncthreads();

    f32x4 z = {0.f, 0.f, 0.f, 0.f};
    f32x4 acc1[4];
    #pragma unroll
    for (int js = 0; js < 4; js++) acc1[js] = z;
    #pragma unroll
    for (int kc = 0; kc < 8; kc++) {
        bf16x8 b = *(const bf16x8*)&lH[l16][kc * 32 + quad * 8];
        #pragma unroll
        for (int js = 0; js < 4; js++) {
            bf16x8 a = *(const bf16x8*)&W1t[(long)(w * 64 + js * 16 + l16) * 256 + kc * 32 + quad * 8];
            acc1[js] = __builtin_amdgcn_mfma_f32_16x16x32_bf16(a, b, acc1[js], 0, 0, 0);
        }
    }
    #pragma unroll
    for (int js = 0; js < 4; js++) {
        u32 e[4];
        #pragma unroll
        for (int r = 0; r < 4; r++) {
            int j = w * 64 + js * 16 + quad * 4 + r;
            float v = acc1[js][r] + b1v[j];
            float g = 0.5f * v * (1.f + erff(v * 0.70710678118f));
            u32 u = __float_as_uint(g);
            e[r] = u + 0x7fffu + ((u >> 16) & 1u);
        }
        uint2 pk;
        pk.x = __builtin_amdgcn_perm(e[1], e[0], 0x07060302u);
        pk.y = __builtin_amdgcn_perm(e[3], e[2], 0x07060302u);
        *(uint2*)&lT[l16][w * 64 + js * 16 + quad * 4] = pk;
    }
    __syncthreads();
    f32x4 acc2[4];
    #pragma unroll
    for (int cs = 0; cs < 4; cs++) acc2[cs] = z;
    #pragma unroll
    for (int kc = 0; kc < 8; kc++) {
        bf16x8 pa = *(const bf16x8*)&lT[l16][kc * 32 + quad * 8];
        #pragma unroll
        for (int cs = 0; cs < 4; cs++) {
            bf16x8 wb = *(const bf16x8*)&W2t[(long)(w * 64 + cs * 16 + l16) * 256 + kc * 32 + quad * 8];
            acc2[cs] = __builtin_amdgcn_mfma_f32_16x16x32_bf16(pa, wb, acc2[cs], 0, 0, 0);
        }
    }
    #pragma unroll
    for (int cs = 0; cs < 4; cs++) {
        int c = w * 64 + cs * 16 + l16;
        float bj = b2v[c];
        float vv[4];
        #pragma unroll
        for (int r = 0; r < 4; r++)
            vv[r] = acc2[cs][r] + bj + aF[quad * 4 + r][c];
        float4 o = make_float4(vv[0], vv[1], vv[2], vv[3]);
        *(float4*)&out[((long)n * 256 + c) * SEQ + s0 + quad * 4] = o;
    }
}

// ---------------------------------------------------------------------------
extern "C" void kernel_launch(void* const* d_in, const int* in_sizes, int n_in,
                              void* d_out, int out_size, void* d_ws, size_t ws_size,
                              hipStream_t stream) {
    const float* x    = (const float*)d_in[0];
    const float* ln1w = (const float*)d_in[1];
    const float* ln1b = (const float*)d_in[2];
    const float* WQ   = (const float*)d_in[3];
    const float* WK   = (const float*)d_in[4];
    const float* WV   = (const float*)d_in[5];
    const float* ln2w = (const float*)d_in[6];
    const float* ln2b = (const float*)d_in[7];
    const float* W1   = (const float*)d_in[8];
    const float* b1   = (const float*)d_in[9];
    const float* W2   = (const float*)d_in[10];
    const float* b2   = (const float*)d_in[11];
    float* out = (float*)d_out;

    char* p = (char*)d_ws;
    u16* norm   = (u16*)p;   p += (size_t)8192 * 256 * 2;
    u16* BtQKV  = (u16*)p;   p += (size_t)768 * 256 * 2;
    u16* W1t    = (u16*)p;   p += (size_t)256 * 256 * 2;
    u16* W2t    = (u16*)p;   p += (size_t)256 * 256 * 2;
    u16* Qb     = (u16*)p;   p += (size_t)NHT * SEQ * 64 * 2;
    u16* Kb     = (u16*)p;   p += (size_t)NHT * SEQ * 64 * 2;
    u16* VtT    = (u16*)p;   p += (size_t)NHT * SEQ * 64 * 2;
    float* D2   = (float*)p; p += (size_t)2 * NHT * SEQ * 4;
    float* acat2= (float*)p; p += (size_t)2 * 8192 * 256 * 4;

    k_prep<<<1536, 256, 0, stream>>>(x, ln1w, ln1b, WQ, WK, WV, W1, W2,
                                     norm, BtQKV, W1t, W2t);
    k_qkv<<<dim3(128, 6), 256, 0, stream>>>(norm, BtQKV, Qb, Kb, VtT);
    k_pass1<<<dim3(32, 8, 2), 256, 0, stream>>>(Qb, Kb, D2);
    k_pass2<<<dim3(32, 8, 2), 256, 0, stream>>>(Qb, Kb, VtT, D2, acat2);
    k_tail<<<512, 256, 0, stream>>>(x, acat2, ln2w, ln2b, W1t, b1, W2t, b2, out);
}